// Round 1
// baseline (185.914 us; speedup 1.0000x reference)
//
#include <hip/hip_runtime.h>
#include <hip/hip_bf16.h>

// CustomAttention: proj = tanh(H @ W^T + b); scores = proj @ c; attn = softmax_L(scores);
// out0 = sum_l H * attn ; out1 = attn.
// B=64, L=512, D=768.  M = B*L = 32768 rows.
// Strategy: split-bf16 MFMA GEMM (K = 3*768 = 2304: hh*wh + hl*wh + hh*wl) with fused
// tanh/context epilogue -> partial scores; then softmax; then weighted sum.

typedef __attribute__((ext_vector_type(8))) short short8;   // 8 bf16 = 4 VGPRs (MFMA A/B frag)
typedef __attribute__((ext_vector_type(4))) float f32x4;    // MFMA C/D frag

#define AS1 __attribute__((address_space(1)))
#define AS3 __attribute__((address_space(3)))

__device__ __forceinline__ void gload_lds16(const void* g, void* l) {
  __builtin_amdgcn_global_load_lds((const AS1 void*)g, (AS3 void*)l, 16, 0, 0);
}

// bf16 round-to-nearest-even split helpers
__device__ __forceinline__ unsigned short f2bf_rne(float x) {
  unsigned u = __float_as_uint(x);
  u += 0x7fffu + ((u >> 16) & 1u);
  return (unsigned short)(u >> 16);
}
__device__ __forceinline__ float bf2f(unsigned short h) {
  return __uint_as_float(((unsigned)h) << 16);
}

// ---------------- conversion kernels ----------------

// H (fp32 [32768][768]) -> A_hi, A_lo (bf16 [32768][768])
__global__ void convert_h(const float4* __restrict__ H4,
                          ushort* __restrict__ Ahi, ushort* __restrict__ Alo) {
  int i = blockIdx.x * 256 + threadIdx.x;   // quad index, 6291456 total
  float4 x = H4[i];
  ushort4 hv, lv;
  hv.x = f2bf_rne(x.x); lv.x = f2bf_rne(x.x - bf2f(hv.x));
  hv.y = f2bf_rne(x.y); lv.y = f2bf_rne(x.y - bf2f(hv.y));
  hv.z = f2bf_rne(x.z); lv.z = f2bf_rne(x.z - bf2f(hv.z));
  hv.w = f2bf_rne(x.w); lv.w = f2bf_rne(x.w - bf2f(hv.w));
  ((ushort4*)Ahi)[i] = hv;
  ((ushort4*)Alo)[i] = lv;
}

// W (fp32 [768 e][768 d]) -> Wt (bf16 [768 e][2304 k]) with k-blocks [w_hi | w_hi | w_lo]
// pairing A' k-blocks [h_hi | h_lo | h_hi]
__global__ void convert_w(const float* __restrict__ W, ushort* __restrict__ Wt) {
  int idx = blockIdx.x * 256 + threadIdx.x;   // 589824 total
  int e = idx / 768, d = idx - e * 768;
  float x = W[idx];
  unsigned short hi = f2bf_rne(x);
  unsigned short lo = f2bf_rne(x - bf2f(hi));
  Wt[e * 2304 + d]        = hi;
  Wt[e * 2304 + 768 + d]  = hi;
  Wt[e * 2304 + 1536 + d] = lo;
}

// ---------------- fused GEMM + tanh/context epilogue ----------------
// Tile 128(M) x 128(N), BK=64, 256 threads = 4 waves in 2x2, each wave 64x64
// (4x4 frags of mfma_f32_16x16x32_bf16).  K-loop over 36 blocks of 64 (K=2304).
// LDS tiles are [row][64 k] bf16 = 128 B rows with XOR swizzle byte ^= (row&7)<<4,
// applied on the pre-swizzled global source (global_load_lds writes linearly) and
// on the ds_read address (rule #21: both-sides-or-neither).
__global__ __launch_bounds__(256) void gemm_scores(
    const ushort* __restrict__ Ahi, const ushort* __restrict__ Alo,
    const ushort* __restrict__ Wt, const float* __restrict__ bias,
    const float* __restrict__ cvec, float* __restrict__ part) {
  __shared__ ushort ldsA[128 * 64];   // 16 KB
  __shared__ ushort ldsB[128 * 64];   // 16 KB
  __shared__ float scpart[2][128];

  const int tid = threadIdx.x;
  const int lane = tid & 63;
  const int wid = tid >> 6;           // 0..3
  const int wr = wid >> 1, wc = wid & 1;
  const int m = lane & 15, q = lane >> 4;
  const int mtile = blockIdx.x, ntile = blockIdx.y;

  f32x4 acc[4][4];
  #pragma unroll
  for (int a = 0; a < 4; ++a)
    #pragma unroll
    for (int b2 = 0; b2 < 4; ++b2)
      acc[a][b2] = (f32x4){0.f, 0.f, 0.f, 0.f};

  const char* const wtbase = (const char*)Wt + (size_t)(ntile * 128) * 4608;
  char* const ldsAw = (char*)ldsA + (wid << 10);
  char* const ldsBw = (char*)ldsB + (wid << 10);

  for (int kb = 0; kb < 36; ++kb) {
    const ushort* Asrc; int k0;
    if (kb < 12)      { Asrc = Ahi; k0 = kb * 64; }         // h_hi * w_hi
    else if (kb < 24) { Asrc = Alo; k0 = (kb - 12) * 64; }  // h_lo * w_hi
    else              { Asrc = Ahi; k0 = (kb - 24) * 64; }  // h_hi * w_lo

    const char* abase = (const char*)Asrc + (size_t)(mtile * 128) * 1536 + k0 * 2;
    const char* bbase = wtbase + kb * 128;

    // stage A tile [128][64]bf16 (4 rounds x 256 thr x 16B) and B tile likewise
    #pragma unroll
    for (int r = 0; r < 4; ++r) {
      int off = tid * 16 + r * 4096;
      int row = off >> 7;
      int col = (off & 127) ^ ((row & 7) << 4);     // inverse-swizzled source
      gload_lds16(abase + row * 1536 + col, ldsAw + r * 4096);
    }
    #pragma unroll
    for (int r = 0; r < 4; ++r) {
      int off = tid * 16 + r * 4096;
      int row = off >> 7;
      int col = (off & 127) ^ ((row & 7) << 4);
      gload_lds16(bbase + row * 4608 + col, ldsBw + r * 4096);
    }
    __syncthreads();   // compiler drains vmcnt(0) before barrier

    #pragma unroll
    for (int ks = 0; ks < 2; ++ks) {
      short8 areg[4], breg[4];
      #pragma unroll
      for (int mi = 0; mi < 4; ++mi) {
        int row = wr * 64 + mi * 16 + m;
        int col = (ks * 64 + q * 16) ^ ((row & 7) << 4);  // swizzled read
        areg[mi] = *(const short8*)((const char*)ldsA + row * 128 + col);
      }
      #pragma unroll
      for (int ni = 0; ni < 4; ++ni) {
        int row = wc * 64 + ni * 16 + m;
        int col = (ks * 64 + q * 16) ^ ((row & 7) << 4);
        breg[ni] = *(const short8*)((const char*)ldsB + row * 128 + col);
      }
      #pragma unroll
      for (int mi = 0; mi < 4; ++mi)
        #pragma unroll
        for (int ni = 0; ni < 4; ++ni)
          acc[mi][ni] = __builtin_amdgcn_mfma_f32_16x16x32_bf16(
              areg[mi], breg[ni], acc[mi][ni], 0, 0, 0);
    }
    __syncthreads();
  }

  // epilogue: score partial = sum_e tanh(acc + b[e]) * c[e], reduced per row
  float bb[4], cc[4];
  #pragma unroll
  for (int ni = 0; ni < 4; ++ni) {
    int e = ntile * 128 + wc * 64 + ni * 16 + m;
    bb[ni] = bias[e];
    cc[ni] = cvec[e];
  }
  #pragma unroll
  for (int mi = 0; mi < 4; ++mi) {
    #pragma unroll
    for (int j = 0; j < 4; ++j) {
      float s = 0.f;
      #pragma unroll
      for (int ni = 0; ni < 4; ++ni)
        s += tanhf(acc[mi][ni][j] + bb[ni]) * cc[ni];
      // reduce across the 16 lanes sharing this C row (lane&15 varies)
      s += __shfl_xor(s, 1);
      s += __shfl_xor(s, 2);
      s += __shfl_xor(s, 4);
      s += __shfl_xor(s, 8);
      if (m == 0) scpart[wc][wr * 64 + mi * 16 + q * 4 + j] = s;
    }
  }
  __syncthreads();
  if (tid < 128)
    part[ntile * 32768 + mtile * 128 + tid] = scpart[0][tid] + scpart[1][tid];
}

// ---------------- softmax over L per batch ----------------
__global__ void softmax_k(const float* __restrict__ part, float* __restrict__ attn) {
  int b = blockIdx.x, l = threadIdx.x;       // 512 threads
  int r = b * 512 + l;
  float s = part[r] + part[32768 + r] + part[2 * 32768 + r] +
            part[3 * 32768 + r] + part[4 * 32768 + r] + part[5 * 32768 + r];
  __shared__ float redm[8], reds[8];
  float mx = s;
  #pragma unroll
  for (int o = 32; o >= 1; o >>= 1) mx = fmaxf(mx, __shfl_xor(mx, o));
  if ((l & 63) == 0) redm[l >> 6] = mx;
  __syncthreads();
  mx = redm[0];
  #pragma unroll
  for (int i = 1; i < 8; ++i) mx = fmaxf(mx, redm[i]);
  float e = expf(s - mx);
  float sm = e;
  #pragma unroll
  for (int o = 32; o >= 1; o >>= 1) sm += __shfl_xor(sm, o);
  if ((l & 63) == 0) reds[l >> 6] = sm;
  __syncthreads();
  float tot = reds[0];
  #pragma unroll
  for (int i = 1; i < 8; ++i) tot += reds[i];
  attn[r] = e / tot;
}

// ---------------- weighted sum over L ----------------
__global__ void wsum_k(const float* __restrict__ H, const float* __restrict__ attn,
                       float* __restrict__ out) {
  int b = blockIdx.x, dc = blockIdx.y;       // grid (64, 3), 256 threads
  int t = threadIdx.x;
  __shared__ float w[512];
  w[t] = attn[b * 512 + t];
  w[t + 256] = attn[b * 512 + 256 + t];
  __syncthreads();
  int d = dc * 256 + t;
  const float* hp = H + (size_t)b * 512 * 768 + d;
  float acc = 0.f;
  #pragma unroll 8
  for (int l = 0; l < 512; ++l) acc += hp[(size_t)l * 768] * w[l];
  out[b * 768 + d] = acc;
}

// ---------------- launch ----------------
extern "C" void kernel_launch(void* const* d_in, const int* in_sizes, int n_in,
                              void* d_out, int out_size, void* d_ws, size_t ws_size,
                              hipStream_t stream) {
  const float* H    = (const float*)d_in[0];   // [64,512,768]
  const float* W    = (const float*)d_in[1];   // [768,768]
  const float* bias = (const float*)d_in[2];   // [768]
  const float* cvec = (const float*)d_in[3];   // [768,1]
  float* out = (float*)d_out;                  // [0,49152): weighted ; [49152,81920): attn

  char* ws = (char*)d_ws;
  ushort* Ahi = (ushort*)(ws + 0);             // 50,331,648 B
  ushort* Alo = (ushort*)(ws + 50331648);      // 50,331,648 B
  ushort* Wt  = (ushort*)(ws + 100663296);     //  3,538,944 B
  float*  prt = (float*) (ws + 104202240);     //    786,432 B  ([6][32768])

  hipLaunchKernelGGL(convert_h, dim3(24576), dim3(256), 0, stream,
                     (const float4*)H, Ahi, Alo);
  hipLaunchKernelGGL(convert_w, dim3(2304), dim3(256), 0, stream, W, Wt);
  hipLaunchKernelGGL(gemm_scores, dim3(256, 6), dim3(256), 0, stream,
                     Ahi, Alo, Wt, bias, cvec, prt);
  hipLaunchKernelGGL(softmax_k, dim3(64), dim3(512), 0, stream, prt, out + 49152);
  hipLaunchKernelGGL(wsum_k, dim3(64, 3), dim3(256), 0, stream,
                     H, out + 49152, out);
}

// Round 2
// 136.904 us; speedup vs baseline: 1.3580x; 1.3580x over previous
//
#include <hip/hip_runtime.h>
#include <hip/hip_bf16.h>

// CustomAttention: proj = tanh(H @ W^T + b); scores = proj @ c; attn = softmax_L(scores);
// out0 = sum_l H * attn ; out1 = attn.
// B=64, L=512, D=768.  M = B*L = 32768 rows.
// Round 2: single fp16 MFMA GEMM (K=768). fp16 (11-bit significand) gives
// score error ~0.011 << 0.0856 threshold while cutting GEMM FLOPs 3x vs the
// round-1 split-bf16 K=2304 scheme.

using half8 = __attribute__((ext_vector_type(8))) _Float16;   // MFMA A/B frag (4 VGPRs)
using f32x4 = __attribute__((ext_vector_type(4))) float;      // MFMA C/D frag

#define AS1 __attribute__((address_space(1)))
#define AS3 __attribute__((address_space(3)))

__device__ __forceinline__ void gload_lds16(const void* g, void* l) {
  __builtin_amdgcn_global_load_lds((const AS1 void*)g, (AS3 void*)l, 16, 0, 0);
}

__device__ __forceinline__ unsigned short f2h(float x) {
  _Float16 h = (_Float16)x;                       // v_cvt_f16_f32, RNE
  return __builtin_bit_cast(unsigned short, h);
}

// ---------------- conversion kernels ----------------

// H (fp32 [32768][768]) -> Ah (f16 [32768][768])
__global__ void convert_h(const float4* __restrict__ H4, ushort4* __restrict__ Ah) {
  int i = blockIdx.x * 256 + threadIdx.x;   // quad index, 6291456 total
  float4 x = H4[i];
  ushort4 o;
  o.x = f2h(x.x); o.y = f2h(x.y); o.z = f2h(x.z); o.w = f2h(x.w);
  Ah[i] = o;
}

// W (fp32 [768][768]) -> Wt (f16 [768][768])
__global__ void convert_w(const float4* __restrict__ W4, ushort4* __restrict__ Wt) {
  int i = blockIdx.x * 256 + threadIdx.x;   // 147456 quads
  float4 x = W4[i];
  ushort4 o;
  o.x = f2h(x.x); o.y = f2h(x.y); o.z = f2h(x.z); o.w = f2h(x.w);
  Wt[i] = o;
}

// ---------------- fused GEMM + tanh/context epilogue ----------------
// Tile 128(M) x 128(N), BK=64, 256 threads = 4 waves in 2x2, each wave 64x64
// (4x4 frags of mfma_f32_16x16x32_f16).  K-loop over 12 blocks of 64 (K=768).
// LDS tiles [row][64 k] f16 = 128 B rows, XOR swizzle byte ^= (row&7)<<4 applied
// both-sides (pre-swizzled global source + swizzled ds_read).
__global__ __launch_bounds__(256) void gemm_scores(
    const ushort* __restrict__ Ah, const ushort* __restrict__ Wt,
    const float* __restrict__ bias, const float* __restrict__ cvec,
    float* __restrict__ part) {
  __shared__ ushort ldsA[128 * 64];   // 16 KB
  __shared__ ushort ldsB[128 * 64];   // 16 KB
  __shared__ float scpart[2][128];

  const int tid = threadIdx.x;
  const int lane = tid & 63;
  const int wid = tid >> 6;           // 0..3
  const int wr = wid >> 1, wc = wid & 1;
  const int m = lane & 15, q = lane >> 4;
  const int mtile = blockIdx.x, ntile = blockIdx.y;

  f32x4 acc[4][4];
  #pragma unroll
  for (int a = 0; a < 4; ++a)
    #pragma unroll
    for (int b2 = 0; b2 < 4; ++b2)
      acc[a][b2] = (f32x4){0.f, 0.f, 0.f, 0.f};

  const char* const abase0 = (const char*)Ah + (size_t)(mtile * 128) * 1536;
  const char* const bbase0 = (const char*)Wt + (size_t)(ntile * 128) * 1536;
  char* const ldsAw = (char*)ldsA + (wid << 10);
  char* const ldsBw = (char*)ldsB + (wid << 10);

  for (int kb = 0; kb < 12; ++kb) {
    const char* abase = abase0 + kb * 128;
    const char* bbase = bbase0 + kb * 128;

    // stage A tile [128][64]f16 (4 rounds x 256 thr x 16B) and B tile likewise
    #pragma unroll
    for (int r = 0; r < 4; ++r) {
      int off = tid * 16 + r * 4096;
      int row = off >> 7;
      int col = (off & 127) ^ ((row & 7) << 4);     // inverse-swizzled source
      gload_lds16(abase + row * 1536 + col, ldsAw + r * 4096);
    }
    #pragma unroll
    for (int r = 0; r < 4; ++r) {
      int off = tid * 16 + r * 4096;
      int row = off >> 7;
      int col = (off & 127) ^ ((row & 7) << 4);
      gload_lds16(bbase + row * 1536 + col, ldsBw + r * 4096);
    }
    __syncthreads();   // compiler drains vmcnt(0) before barrier

    #pragma unroll
    for (int ks = 0; ks < 2; ++ks) {
      half8 areg[4], breg[4];
      #pragma unroll
      for (int mi = 0; mi < 4; ++mi) {
        int row = wr * 64 + mi * 16 + m;
        int col = (ks * 64 + q * 16) ^ ((row & 7) << 4);  // swizzled read
        areg[mi] = *(const half8*)((const char*)ldsA + row * 128 + col);
      }
      #pragma unroll
      for (int ni = 0; ni < 4; ++ni) {
        int row = wc * 64 + ni * 16 + m;
        int col = (ks * 64 + q * 16) ^ ((row & 7) << 4);
        breg[ni] = *(const half8*)((const char*)ldsB + row * 128 + col);
      }
      #pragma unroll
      for (int mi = 0; mi < 4; ++mi)
        #pragma unroll
        for (int ni = 0; ni < 4; ++ni)
          acc[mi][ni] = __builtin_amdgcn_mfma_f32_16x16x32_f16(
              areg[mi], breg[ni], acc[mi][ni], 0, 0, 0);
    }
    __syncthreads();
  }

  // epilogue: score partial = sum_e tanh(acc + b[e]) * c[e], reduced per row
  float bb[4], cc[4];
  #pragma unroll
  for (int ni = 0; ni < 4; ++ni) {
    int e = ntile * 128 + wc * 64 + ni * 16 + m;
    bb[ni] = bias[e];
    cc[ni] = cvec[e];
  }
  #pragma unroll
  for (int mi = 0; mi < 4; ++mi) {
    #pragma unroll
    for (int j = 0; j < 4; ++j) {
      float s = 0.f;
      #pragma unroll
      for (int ni = 0; ni < 4; ++ni)
        s += tanhf(acc[mi][ni][j] + bb[ni]) * cc[ni];
      // reduce across the 16 lanes sharing this C row (lane&15 = e varies)
      s += __shfl_xor(s, 1);
      s += __shfl_xor(s, 2);
      s += __shfl_xor(s, 4);
      s += __shfl_xor(s, 8);
      if (m == 0) scpart[wc][wr * 64 + mi * 16 + q * 4 + j] = s;
    }
  }
  __syncthreads();
  if (tid < 128)
    part[ntile * 32768 + mtile * 128 + tid] = scpart[0][tid] + scpart[1][tid];
}

// ---------------- softmax over L per batch ----------------
__global__ void softmax_k(const float* __restrict__ part, float* __restrict__ attn) {
  int b = blockIdx.x, l = threadIdx.x;       // 512 threads
  int r = b * 512 + l;
  float s = part[r] + part[32768 + r] + part[2 * 32768 + r] +
            part[3 * 32768 + r] + part[4 * 32768 + r] + part[5 * 32768 + r];
  __shared__ float redm[8], reds[8];
  float mx = s;
  #pragma unroll
  for (int o = 32; o >= 1; o >>= 1) mx = fmaxf(mx, __shfl_xor(mx, o));
  if ((l & 63) == 0) redm[l >> 6] = mx;
  __syncthreads();
  mx = redm[0];
  #pragma unroll
  for (int i = 1; i < 8; ++i) mx = fmaxf(mx, redm[i]);
  float e = expf(s - mx);
  float sm = e;
  #pragma unroll
  for (int o = 32; o >= 1; o >>= 1) sm += __shfl_xor(sm, o);
  if ((l & 63) == 0) reds[l >> 6] = sm;
  __syncthreads();
  float tot = reds[0];
  #pragma unroll
  for (int i = 1; i < 8; ++i) tot += reds[i];
  attn[r] = e / tot;
}

// ---------------- weighted sum over L ----------------
__global__ void wsum_k(const float* __restrict__ H, const float* __restrict__ attn,
                       float* __restrict__ out) {
  int b = blockIdx.x, dc = blockIdx.y;       // grid (64, 3), 256 threads
  int t = threadIdx.x;
  __shared__ float w[512];
  w[t] = attn[b * 512 + t];
  w[t + 256] = attn[b * 512 + 256 + t];
  __syncthreads();
  int d = dc * 256 + t;
  const float* hp = H + (size_t)b * 512 * 768 + d;
  float acc = 0.f;
  #pragma unroll 8
  for (int l = 0; l < 512; ++l) acc += hp[(size_t)l * 768] * w[l];
  out[b * 768 + d] = acc;
}

// ---------------- launch ----------------
extern "C" void kernel_launch(void* const* d_in, const int* in_sizes, int n_in,
                              void* d_out, int out_size, void* d_ws, size_t ws_size,
                              hipStream_t stream) {
  const float* H    = (const float*)d_in[0];   // [64,512,768]
  const float* W    = (const float*)d_in[1];   // [768,768]
  const float* bias = (const float*)d_in[2];   // [768]
  const float* cvec = (const float*)d_in[3];   // [768,1]
  float* out = (float*)d_out;                  // [0,49152): weighted ; [49152,81920): attn

  char* ws = (char*)d_ws;
  ushort* Ah = (ushort*)(ws + 0);              // 50,331,648 B
  ushort* Wt = (ushort*)(ws + 50331648);       //  1,179,648 B
  float*  prt = (float*)(ws + 51511296);       //    786,432 B  ([6][32768])

  hipLaunchKernelGGL(convert_h, dim3(24576), dim3(256), 0, stream,
                     (const float4*)H, (ushort4*)Ah);
  hipLaunchKernelGGL(convert_w, dim3(576), dim3(256), 0, stream,
                     (const float4*)W, (ushort4*)Wt);
  hipLaunchKernelGGL(gemm_scores, dim3(256, 6), dim3(256), 0, stream,
                     Ah, Wt, bias, cvec, prt);
  hipLaunchKernelGGL(softmax_k, dim3(64), dim3(512), 0, stream, prt, out + 49152);
  hipLaunchKernelGGL(wsum_k, dim3(64, 3), dim3(256), 0, stream,
                     H, out + 49152, out);
}

// Round 3
// 124.100 us; speedup vs baseline: 1.4981x; 1.1032x over previous
//
#include <hip/hip_runtime.h>
#include <hip/hip_bf16.h>

// CustomAttention: proj = tanh(H @ W^T + b); scores = proj @ c; attn = softmax_L(scores);
// out0 = sum_l H * attn ; out1 = attn.
// B=64, L=512, D=768.  M = B*L = 32768 rows.
// Round 3: XCD-affinity block swizzle so the 6 same-mtile blocks (which re-read
// the same 196 KB A-tile) land on the SAME XCD, adjacent in dispatch order ->
// A re-reads become L2 hits instead of ~2.5 TB/s L3 streams. wsum reads f16 Ah.

using half8 = __attribute__((ext_vector_type(8))) _Float16;   // MFMA A/B frag (4 VGPRs)
using f32x4 = __attribute__((ext_vector_type(4))) float;      // MFMA C/D frag

#define AS1 __attribute__((address_space(1)))
#define AS3 __attribute__((address_space(3)))

__device__ __forceinline__ void gload_lds16(const void* g, void* l) {
  __builtin_amdgcn_global_load_lds((const AS1 void*)g, (AS3 void*)l, 16, 0, 0);
}

__device__ __forceinline__ unsigned short f2h(float x) {
  _Float16 h = (_Float16)x;                       // v_cvt_f16_f32, RNE
  return __builtin_bit_cast(unsigned short, h);
}

// ---------------- conversion kernels ----------------

// H (fp32 [32768][768]) -> Ah (f16 [32768][768])
__global__ void convert_h(const float4* __restrict__ H4, ushort4* __restrict__ Ah) {
  int i = blockIdx.x * 256 + threadIdx.x;   // quad index, 6291456 total
  float4 x = H4[i];
  ushort4 o;
  o.x = f2h(x.x); o.y = f2h(x.y); o.z = f2h(x.z); o.w = f2h(x.w);
  Ah[i] = o;
}

// W (fp32 [768][768]) -> Wt (f16 [768][768])
__global__ void convert_w(const float4* __restrict__ W4, ushort4* __restrict__ Wt) {
  int i = blockIdx.x * 256 + threadIdx.x;   // 147456 quads
  float4 x = W4[i];
  ushort4 o;
  o.x = f2h(x.x); o.y = f2h(x.y); o.z = f2h(x.z); o.w = f2h(x.w);
  Wt[i] = o;
}

// ---------------- fused GEMM + tanh/context epilogue ----------------
// Tile 128(M) x 128(N), BK=64, 256 threads = 4 waves in 2x2, each wave 64x64
// (4x4 frags of mfma_f32_16x16x32_f16).  K-loop over 12 blocks of 64 (K=768).
// LDS tiles [row][64 k] f16 = 128 B rows, XOR swizzle byte ^= (row&7)<<4 applied
// both-sides (pre-swizzled global source + swizzled ds_read).
// Grid: flat 1536 blocks.  XCD-affinity decode: xcd = bid&7 (id%8 round-robin),
// slot = bid>>3; mtile = xcd*32 + slot/6, ntile = slot%6.  The 6 blocks sharing
// an mtile have ids {xcd + 8*(6m..6m+5)} -> same XCD, adjacent slots -> the
// A-tile stays in that XCD's 4 MB L2 across all 6 ntile passes.
__global__ __launch_bounds__(256) void gemm_scores(
    const ushort* __restrict__ Ah, const ushort* __restrict__ Wt,
    const float* __restrict__ bias, const float* __restrict__ cvec,
    float* __restrict__ part) {
  __shared__ ushort ldsA[128 * 64];   // 16 KB
  __shared__ ushort ldsB[128 * 64];   // 16 KB
  __shared__ float scpart[2][128];

  const int tid = threadIdx.x;
  const int lane = tid & 63;
  const int wid = tid >> 6;           // 0..3
  const int wr = wid >> 1, wc = wid & 1;
  const int m = lane & 15, q = lane >> 4;

  const int bid = blockIdx.x;        // 0..1535
  const int xcd = bid & 7;
  const int slot = bid >> 3;          // 0..191
  const int mtile = xcd * 32 + slot / 6;
  const int ntile = slot % 6;

  f32x4 acc[4][4];
  #pragma unroll
  for (int a = 0; a < 4; ++a)
    #pragma unroll
    for (int b2 = 0; b2 < 4; ++b2)
      acc[a][b2] = (f32x4){0.f, 0.f, 0.f, 0.f};

  const char* const abase0 = (const char*)Ah + (size_t)(mtile * 128) * 1536;
  const char* const bbase0 = (const char*)Wt + (size_t)(ntile * 128) * 1536;
  char* const ldsAw = (char*)ldsA + (wid << 10);
  char* const ldsBw = (char*)ldsB + (wid << 10);

  for (int kb = 0; kb < 12; ++kb) {
    const char* abase = abase0 + kb * 128;
    const char* bbase = bbase0 + kb * 128;

    // stage A tile [128][64]f16 (4 rounds x 256 thr x 16B) and B tile likewise
    #pragma unroll
    for (int r = 0; r < 4; ++r) {
      int off = tid * 16 + r * 4096;
      int row = off >> 7;
      int col = (off & 127) ^ ((row & 7) << 4);     // inverse-swizzled source
      gload_lds16(abase + row * 1536 + col, ldsAw + r * 4096);
    }
    #pragma unroll
    for (int r = 0; r < 4; ++r) {
      int off = tid * 16 + r * 4096;
      int row = off >> 7;
      int col = (off & 127) ^ ((row & 7) << 4);
      gload_lds16(bbase + row * 1536 + col, ldsBw + r * 4096);
    }
    __syncthreads();   // compiler drains vmcnt(0) before barrier

    #pragma unroll
    for (int ks = 0; ks < 2; ++ks) {
      half8 areg[4], breg[4];
      #pragma unroll
      for (int mi = 0; mi < 4; ++mi) {
        int row = wr * 64 + mi * 16 + m;
        int col = (ks * 64 + q * 16) ^ ((row & 7) << 4);  // swizzled read
        areg[mi] = *(const half8*)((const char*)ldsA + row * 128 + col);
      }
      #pragma unroll
      for (int ni = 0; ni < 4; ++ni) {
        int row = wc * 64 + ni * 16 + m;
        int col = (ks * 64 + q * 16) ^ ((row & 7) << 4);
        breg[ni] = *(const half8*)((const char*)ldsB + row * 128 + col);
      }
      #pragma unroll
      for (int mi = 0; mi < 4; ++mi)
        #pragma unroll
        for (int ni = 0; ni < 4; ++ni)
          acc[mi][ni] = __builtin_amdgcn_mfma_f32_16x16x32_f16(
              areg[mi], breg[ni], acc[mi][ni], 0, 0, 0);
    }
    __syncthreads();
  }

  // epilogue: score partial = sum_e tanh(acc + b[e]) * c[e], reduced per row
  float bb[4], cc[4];
  #pragma unroll
  for (int ni = 0; ni < 4; ++ni) {
    int e = ntile * 128 + wc * 64 + ni * 16 + m;
    bb[ni] = bias[e];
    cc[ni] = cvec[e];
  }
  #pragma unroll
  for (int mi = 0; mi < 4; ++mi) {
    #pragma unroll
    for (int j = 0; j < 4; ++j) {
      float s = 0.f;
      #pragma unroll
      for (int ni = 0; ni < 4; ++ni)
        s += tanhf(acc[mi][ni][j] + bb[ni]) * cc[ni];
      // reduce across the 16 lanes sharing this C row (lane&15 = e varies)
      s += __shfl_xor(s, 1);
      s += __shfl_xor(s, 2);
      s += __shfl_xor(s, 4);
      s += __shfl_xor(s, 8);
      if (m == 0) scpart[wc][wr * 64 + mi * 16 + q * 4 + j] = s;
    }
  }
  __syncthreads();
  if (tid < 128)
    part[ntile * 32768 + mtile * 128 + tid] = scpart[0][tid] + scpart[1][tid];
}

// ---------------- softmax over L per batch ----------------
__global__ void softmax_k(const float* __restrict__ part, float* __restrict__ attn) {
  int b = blockIdx.x, l = threadIdx.x;       // 512 threads
  int r = b * 512 + l;
  float s = part[r] + part[32768 + r] + part[2 * 32768 + r] +
            part[3 * 32768 + r] + part[4 * 32768 + r] + part[5 * 32768 + r];
  __shared__ float redm[8], reds[8];
  float mx = s;
  #pragma unroll
  for (int o = 32; o >= 1; o >>= 1) mx = fmaxf(mx, __shfl_xor(mx, o));
  if ((l & 63) == 0) redm[l >> 6] = mx;
  __syncthreads();
  mx = redm[0];
  #pragma unroll
  for (int i = 1; i < 8; ++i) mx = fmaxf(mx, redm[i]);
  float e = expf(s - mx);
  float sm = e;
  #pragma unroll
  for (int o = 32; o >= 1; o >>= 1) sm += __shfl_xor(sm, o);
  if ((l & 63) == 0) reds[l >> 6] = sm;
  __syncthreads();
  float tot = reds[0];
  #pragma unroll
  for (int i = 1; i < 8; ++i) tot += reds[i];
  attn[r] = e / tot;
}

// ---------------- weighted sum over L (reads f16 Ah: half the bytes, L3-hot) ----
__global__ void wsum_k(const _Float16* __restrict__ Ah, const float* __restrict__ attn,
                       float* __restrict__ out) {
  int b = blockIdx.x, dc = blockIdx.y;       // grid (64, 3), 256 threads
  int t = threadIdx.x;
  __shared__ float w[512];
  w[t] = attn[b * 512 + t];
  w[t + 256] = attn[b * 512 + 256 + t];
  __syncthreads();
  int d = dc * 256 + t;
  const _Float16* hp = Ah + (size_t)b * 512 * 768 + d;
  float acc = 0.f;
  #pragma unroll 8
  for (int l = 0; l < 512; ++l) acc += (float)hp[(size_t)l * 768] * w[l];
  out[b * 768 + d] = acc;
}

// ---------------- launch ----------------
extern "C" void kernel_launch(void* const* d_in, const int* in_sizes, int n_in,
                              void* d_out, int out_size, void* d_ws, size_t ws_size,
                              hipStream_t stream) {
  const float* H    = (const float*)d_in[0];   // [64,512,768]
  const float* W    = (const float*)d_in[1];   // [768,768]
  const float* bias = (const float*)d_in[2];   // [768]
  const float* cvec = (const float*)d_in[3];   // [768,1]
  float* out = (float*)d_out;                  // [0,49152): weighted ; [49152,81920): attn

  char* ws = (char*)d_ws;
  ushort* Ah = (ushort*)(ws + 0);              // 50,331,648 B
  ushort* Wt = (ushort*)(ws + 50331648);       //  1,179,648 B
  float*  prt = (float*)(ws + 51511296);       //    786,432 B  ([6][32768])

  hipLaunchKernelGGL(convert_h, dim3(24576), dim3(256), 0, stream,
                     (const float4*)H, (ushort4*)Ah);
  hipLaunchKernelGGL(convert_w, dim3(576), dim3(256), 0, stream,
                     (const float4*)W, (ushort4*)Wt);
  hipLaunchKernelGGL(gemm_scores, dim3(1536), dim3(256), 0, stream,
                     Ah, Wt, bias, cvec, prt);
  hipLaunchKernelGGL(softmax_k, dim3(64), dim3(512), 0, stream, prt, out + 49152);
  hipLaunchKernelGGL(wsum_k, dim3(64, 3), dim3(256), 0, stream,
                     (const _Float16*)Ah, out + 49152, out);
}

// Round 4
// 112.611 us; speedup vs baseline: 1.6509x; 1.1020x over previous
//
#include <hip/hip_runtime.h>
#include <hip/hip_bf16.h>

// CustomAttention: proj = tanh(H @ W^T + b); scores = proj @ c; attn = softmax_L(scores);
// out0 = sum_l H * attn ; out1 = attn.
// B=64, L=512, D=768.  M = B*L = 32768 rows.
// Round 4: T3-minimum 2-phase double-buffered K-loop (stage next tile BEFORE
// computing current; ONE barrier per K-step) + fast tanh epilogue + vectorized wsum.

using half8 = __attribute__((ext_vector_type(8))) _Float16;   // MFMA A/B frag (4 VGPRs)
using f32x4 = __attribute__((ext_vector_type(4))) float;      // MFMA C/D frag

#define AS1 __attribute__((address_space(1)))
#define AS3 __attribute__((address_space(3)))

__device__ __forceinline__ void gload_lds16(const void* g, void* l) {
  __builtin_amdgcn_global_load_lds((const AS1 void*)g, (AS3 void*)l, 16, 0, 0);
}

__device__ __forceinline__ unsigned short f2h(float x) {
  _Float16 h = (_Float16)x;                       // v_cvt_f16_f32, RNE
  return __builtin_bit_cast(unsigned short, h);
}

// tanh(x) = 1 - 2/(exp(2x)+1).  __expf -> v_exp_f32; graceful at +/-inf.
__device__ __forceinline__ float tanh_fast(float x) {
  return 1.0f - __fdividef(2.0f, 1.0f + __expf(2.0f * x));
}

// ---------------- conversion kernels ----------------

// H (fp32 [32768][768]) -> Ah (f16 [32768][768])
__global__ void convert_h(const float4* __restrict__ H4, ushort4* __restrict__ Ah) {
  int i = blockIdx.x * 256 + threadIdx.x;   // quad index, 6291456 total
  float4 x = H4[i];
  ushort4 o;
  o.x = f2h(x.x); o.y = f2h(x.y); o.z = f2h(x.z); o.w = f2h(x.w);
  Ah[i] = o;
}

// W (fp32 [768][768]) -> Wt (f16 [768][768])
__global__ void convert_w(const float4* __restrict__ W4, ushort4* __restrict__ Wt) {
  int i = blockIdx.x * 256 + threadIdx.x;   // 147456 quads
  float4 x = W4[i];
  ushort4 o;
  o.x = f2h(x.x); o.y = f2h(x.y); o.z = f2h(x.z); o.w = f2h(x.w);
  Wt[i] = o;
}

// ---------------- fused GEMM + tanh/context epilogue ----------------
// Tile 128(M) x 128(N), BK=64, 256 threads = 4 waves in 2x2, each wave 64x64
// (4x4 frags of mfma_f32_16x16x32_f16).  K-loop over 12 blocks of 64 (K=768),
// double-buffered LDS (2 x 32 KB): stage tile k+1 while computing tile k,
// single __syncthreads per step (its implicit vmcnt(0) drain lands AFTER the
// compute phase has hidden the load latency).
// LDS tiles [row][64 k] f16 = 128 B rows, XOR swizzle byte ^= (row&7)<<4 applied
// both-sides (pre-swizzled global source + swizzled ds_read).
// Grid: flat 1536 blocks; XCD-affinity decode (bid&7 = XCD round-robin) keeps the
// 6 same-mtile blocks on one XCD, adjacent slots -> A-tile L2 reuse.

__device__ __forceinline__ void stage_tiles(const char* abase, const char* bbase,
                                            char* ldsAbuf, char* ldsBbuf, int tid) {
  char* ldsAw = ldsAbuf + ((tid >> 6) << 10);
  char* ldsBw = ldsBbuf + ((tid >> 6) << 10);
  #pragma unroll
  for (int r = 0; r < 4; ++r) {
    int off = tid * 16 + r * 4096;
    int row = off >> 7;
    int col = (off & 127) ^ ((row & 7) << 4);     // inverse-swizzled source
    gload_lds16(abase + row * 1536 + col, ldsAw + r * 4096);
  }
  #pragma unroll
  for (int r = 0; r < 4; ++r) {
    int off = tid * 16 + r * 4096;
    int row = off >> 7;
    int col = (off & 127) ^ ((row & 7) << 4);
    gload_lds16(bbase + row * 1536 + col, ldsBw + r * 4096);
  }
}

__device__ __forceinline__ void compute_tile(const ushort* ldsAbuf, const ushort* ldsBbuf,
                                             int wr, int wc, int m, int q,
                                             f32x4 acc[4][4]) {
  #pragma unroll
  for (int ks = 0; ks < 2; ++ks) {
    half8 areg[4], breg[4];
    #pragma unroll
    for (int mi = 0; mi < 4; ++mi) {
      int row = wr * 64 + mi * 16 + m;
      int col = (ks * 64 + q * 16) ^ ((row & 7) << 4);  // swizzled read
      areg[mi] = *(const half8*)((const char*)ldsAbuf + row * 128 + col);
    }
    #pragma unroll
    for (int ni = 0; ni < 4; ++ni) {
      int row = wc * 64 + ni * 16 + m;
      int col = (ks * 64 + q * 16) ^ ((row & 7) << 4);
      breg[ni] = *(const half8*)((const char*)ldsBbuf + row * 128 + col);
    }
    #pragma unroll
    for (int mi = 0; mi < 4; ++mi)
      #pragma unroll
      for (int ni = 0; ni < 4; ++ni)
        acc[mi][ni] = __builtin_amdgcn_mfma_f32_16x16x32_f16(
            areg[mi], breg[ni], acc[mi][ni], 0, 0, 0);
  }
}

__global__ __launch_bounds__(256) void gemm_scores(
    const ushort* __restrict__ Ah, const ushort* __restrict__ Wt,
    const float* __restrict__ bias, const float* __restrict__ cvec,
    float* __restrict__ part) {
  __shared__ ushort ldsA[2][8192];    // 2 x 16 KB
  __shared__ ushort ldsB[2][8192];    // 2 x 16 KB
  __shared__ float scpart[2][128];

  const int tid = threadIdx.x;
  const int lane = tid & 63;
  const int wid = tid >> 6;           // 0..3
  const int wr = wid >> 1, wc = wid & 1;
  const int m = lane & 15, q = lane >> 4;

  const int bid = blockIdx.x;         // 0..1535
  const int xcd = bid & 7;
  const int slot = bid >> 3;          // 0..191
  const int mtile = xcd * 32 + slot / 6;
  const int ntile = slot % 6;

  f32x4 acc[4][4];
  #pragma unroll
  for (int a = 0; a < 4; ++a)
    #pragma unroll
    for (int b2 = 0; b2 < 4; ++b2)
      acc[a][b2] = (f32x4){0.f, 0.f, 0.f, 0.f};

  const char* const abase0 = (const char*)Ah + (size_t)(mtile * 128) * 1536;
  const char* const bbase0 = (const char*)Wt + (size_t)(ntile * 128) * 1536;

  // prologue: stage tile 0 into buffer 0
  stage_tiles(abase0, bbase0, (char*)ldsA[0], (char*)ldsB[0], tid);
  __syncthreads();

  #pragma unroll
  for (int kb2 = 0; kb2 < 6; ++kb2) {
    // stage tile 2*kb2+1 into buf1 (always exists: kb2<=5 -> kb<=11)
    stage_tiles(abase0 + (kb2 * 2 + 1) * 128, bbase0 + (kb2 * 2 + 1) * 128,
                (char*)ldsA[1], (char*)ldsB[1], tid);
    compute_tile(ldsA[0], ldsB[0], wr, wc, m, q, acc);
    __syncthreads();                  // drains buf1 stage + all buf0 reads

    if (kb2 < 5)
      stage_tiles(abase0 + (kb2 * 2 + 2) * 128, bbase0 + (kb2 * 2 + 2) * 128,
                  (char*)ldsA[0], (char*)ldsB[0], tid);
    compute_tile(ldsA[1], ldsB[1], wr, wc, m, q, acc);
    __syncthreads();
  }

  // epilogue: score partial = sum_e tanh(acc + b[e]) * c[e], reduced per row
  float bb[4], cc[4];
  #pragma unroll
  for (int ni = 0; ni < 4; ++ni) {
    int e = ntile * 128 + wc * 64 + ni * 16 + m;
    bb[ni] = bias[e];
    cc[ni] = cvec[e];
  }
  #pragma unroll
  for (int mi = 0; mi < 4; ++mi) {
    #pragma unroll
    for (int j = 0; j < 4; ++j) {
      float s = 0.f;
      #pragma unroll
      for (int ni = 0; ni < 4; ++ni)
        s += tanh_fast(acc[mi][ni][j] + bb[ni]) * cc[ni];
      // reduce across the 16 lanes sharing this C row (lane&15 = e varies)
      s += __shfl_xor(s, 1);
      s += __shfl_xor(s, 2);
      s += __shfl_xor(s, 4);
      s += __shfl_xor(s, 8);
      if (m == 0) scpart[wc][wr * 64 + mi * 16 + q * 4 + j] = s;
    }
  }
  __syncthreads();
  if (tid < 128)
    part[ntile * 32768 + mtile * 128 + tid] = scpart[0][tid] + scpart[1][tid];
}

// ---------------- softmax over L per batch ----------------
__global__ void softmax_k(const float* __restrict__ part, float* __restrict__ attn) {
  int b = blockIdx.x, l = threadIdx.x;       // 512 threads
  int r = b * 512 + l;
  float s = part[r] + part[32768 + r] + part[2 * 32768 + r] +
            part[3 * 32768 + r] + part[4 * 32768 + r] + part[5 * 32768 + r];
  __shared__ float redm[8], reds[8];
  float mx = s;
  #pragma unroll
  for (int o = 32; o >= 1; o >>= 1) mx = fmaxf(mx, __shfl_xor(mx, o));
  if ((l & 63) == 0) redm[l >> 6] = mx;
  __syncthreads();
  mx = redm[0];
  #pragma unroll
  for (int i = 1; i < 8; ++i) mx = fmaxf(mx, redm[i]);
  float e = expf(s - mx);
  float sm = e;
  #pragma unroll
  for (int o = 32; o >= 1; o >>= 1) sm += __shfl_xor(sm, o);
  if ((l & 63) == 0) reds[l >> 6] = sm;
  __syncthreads();
  float tot = reds[0];
  #pragma unroll
  for (int i = 1; i < 8; ++i) tot += reds[i];
  attn[r] = e / tot;
}

// ---------------- weighted sum over L (f16 Ah, 2 d's per thread, 4B loads) ----
__global__ void wsum_k(const ushort* __restrict__ Ah, const float* __restrict__ attn,
                       float* __restrict__ out) {
  int b = blockIdx.x, dc = blockIdx.y;       // grid (64, 3), 128 threads
  int t = threadIdx.x;
  __shared__ float w[512];
  #pragma unroll
  for (int i = 0; i < 4; ++i) w[t + i * 128] = attn[b * 512 + t + i * 128];
  __syncthreads();
  int d0 = dc * 256 + t * 2;
  const ushort* hp = Ah + (size_t)b * 512 * 768 + d0;
  float a0 = 0.f, a1 = 0.f;
  #pragma unroll 8
  for (int l = 0; l < 512; ++l) {
    unsigned u = *(const unsigned*)(hp + (size_t)l * 768);
    float wl = w[l];
    a0 += wl * (float)__builtin_bit_cast(_Float16, (unsigned short)(u & 0xffff));
    a1 += wl * (float)__builtin_bit_cast(_Float16, (unsigned short)(u >> 16));
  }
  out[b * 768 + d0] = a0;
  out[b * 768 + d0 + 1] = a1;
}

// ---------------- launch ----------------
extern "C" void kernel_launch(void* const* d_in, const int* in_sizes, int n_in,
                              void* d_out, int out_size, void* d_ws, size_t ws_size,
                              hipStream_t stream) {
  const float* H    = (const float*)d_in[0];   // [64,512,768]
  const float* W    = (const float*)d_in[1];   // [768,768]
  const float* bias = (const float*)d_in[2];   // [768]
  const float* cvec = (const float*)d_in[3];   // [768,1]
  float* out = (float*)d_out;                  // [0,49152): weighted ; [49152,81920): attn

  char* ws = (char*)d_ws;
  ushort* Ah = (ushort*)(ws + 0);              // 50,331,648 B
  ushort* Wt = (ushort*)(ws + 50331648);       //  1,179,648 B
  float*  prt = (float*)(ws + 51511296);       //    786,432 B  ([6][32768])

  hipLaunchKernelGGL(convert_h, dim3(24576), dim3(256), 0, stream,
                     (const float4*)H, (ushort4*)Ah);
  hipLaunchKernelGGL(convert_w, dim3(576), dim3(256), 0, stream,
                     (const float4*)W, (ushort4*)Wt);
  hipLaunchKernelGGL(gemm_scores, dim3(1536), dim3(256), 0, stream,
                     Ah, Wt, bias, cvec, prt);
  hipLaunchKernelGGL(softmax_k, dim3(64), dim3(512), 0, stream, prt, out + 49152);
  hipLaunchKernelGGL(wsum_k, dim3(64, 3), dim3(128), 0, stream,
                     Ah, out + 49152, out);
}